// Round 1
// baseline (12007.561 us; speedup 1.0000x reference)
//
#include <hip/hip_runtime.h>
#include <math.h>

// Problem constants
constexpr int TT = 512;   // sequence length
constexpr int BB = 64;    // batch
constexpr int EE = 256;   // embed dim
constexpr int HH = 256;   // hidden
constexpr int SS = 64;    // states
constexpr int BH = BB * HH;       // 16384
constexpr int G4 = 4 * HH;        // 1024 gates

// ---------------------------------------------------------------------------
// One LSTM time step, both directions. grid = (64, 2): x = u-slice (4 hidden
// units per block), y = direction. 256 threads: lane b = tid&63, uo = tid>>6.
// Each thread owns hidden unit u = bx*4+uo for one batch b: computes the 4
// gate pre-activations (i,f,g,o rows u, 256+u, 512+u, 768+u), K=256 dots
// against h_prev (LDS, transposed) and emb row (global, L2/L3), then the cell
// update. Weights are read through wave-uniform SGPR pointers -> s_load.
// ---------------------------------------------------------------------------
__global__ __launch_bounds__(256) void lstm_step(
    int step,
    const int* __restrict__ obs,
    const float* __restrict__ embed,
    const float* __restrict__ Wih_f, const float* __restrict__ Whh_f,
    const float* __restrict__ bih_f, const float* __restrict__ bhh_f,
    const float* __restrict__ Wih_b, const float* __restrict__ Whh_b,
    const float* __restrict__ bih_b, const float* __restrict__ bhh_b,
    const float* __restrict__ h0, const float* __restrict__ c0,
    float* __restrict__ hsF, float* __restrict__ hsB,
    float* __restrict__ cF, float* __restrict__ cB)
{
    // ht[k][b] = h_prev[b][k]; bank = b%32 -> 2-way (free). 64 KiB exactly.
    __shared__ float ht[256 * 64];

    const int tid = threadIdx.x;
    const int b   = tid & 63;
    const int uo  = tid >> 6;          // wave index, wave-uniform
    const int dir = blockIdx.y;
    const int u   = blockIdx.x * 4 + uo;

    const float* Wih = dir ? Wih_b : Wih_f;
    const float* Whh = dir ? Whh_b : Whh_f;
    const float* bih = dir ? bih_b : bih_f;
    const float* bhh = dir ? bhh_b : bhh_f;
    float* hs = dir ? hsB : hsF;
    float* cS = dir ? cB  : cF;

    const int t_emb = dir ? (TT - 1 - step) : step;   // original time index
    const float* h_prev;
    if (step == 0) {
        h_prev = h0 + dir * BH;
    } else {
        // fwd: previous output at t = step-1. bwd: previous output at t_emb+1.
        const int t_prev = dir ? (t_emb + 1) : (step - 1);
        h_prev = hs + (size_t)t_prev * BH;
    }
    const float* c_prev = (step == 0) ? (c0 + dir * BH) : cS;

    // ---- stage h_prev into LDS transposed ----
    {
        const float4* hp4 = (const float4*)h_prev;   // [b][64 float4]
        #pragma unroll
        for (int it = 0; it < 16; ++it) {
            const int k4 = it * 4 + uo;              // 0..63
            float4 v = hp4[b * 64 + k4];
            const int k = k4 * 4;
            ht[(k + 0) * 64 + b] = v.x;
            ht[(k + 1) * 64 + b] = v.y;
            ht[(k + 2) * 64 + b] = v.z;
            ht[(k + 3) * 64 + b] = v.w;
        }
    }
    __syncthreads();

    // ---- wave-uniform weight row pointers (force SGPR) ----
    const int u_s = __builtin_amdgcn_readfirstlane(u);
    const float4* Wh0 = (const float4*)(Whh + (size_t)(      u_s) * HH);
    const float4* Wh1 = (const float4*)(Whh + (size_t)(256 + u_s) * HH);
    const float4* Wh2 = (const float4*)(Whh + (size_t)(512 + u_s) * HH);
    const float4* Wh3 = (const float4*)(Whh + (size_t)(768 + u_s) * HH);
    const float4* Wi0 = (const float4*)(Wih + (size_t)(      u_s) * EE);
    const float4* Wi1 = (const float4*)(Wih + (size_t)(256 + u_s) * EE);
    const float4* Wi2 = (const float4*)(Wih + (size_t)(512 + u_s) * EE);
    const float4* Wi3 = (const float4*)(Wih + (size_t)(768 + u_s) * EE);

    float a0 = bih[      u_s] + bhh[      u_s];
    float a1 = bih[256 + u_s] + bhh[256 + u_s];
    float a2 = bih[512 + u_s] + bhh[512 + u_s];
    float a3 = bih[768 + u_s] + bhh[768 + u_s];

    // ---- x part: emb row (gathered) dot Wih rows ----
    {
        const int tok = obs[t_emb * BB + b];
        const float4* er4 = (const float4*)(embed + (size_t)tok * EE);
        #pragma unroll 8
        for (int k4 = 0; k4 < 64; ++k4) {
            const float4 xv = er4[k4];
            const float4 w0 = Wi0[k4], w1 = Wi1[k4], w2 = Wi2[k4], w3 = Wi3[k4];
            a0 += xv.x * w0.x; a0 += xv.y * w0.y; a0 += xv.z * w0.z; a0 += xv.w * w0.w;
            a1 += xv.x * w1.x; a1 += xv.y * w1.y; a1 += xv.z * w1.z; a1 += xv.w * w1.w;
            a2 += xv.x * w2.x; a2 += xv.y * w2.y; a2 += xv.z * w2.z; a2 += xv.w * w2.w;
            a3 += xv.x * w3.x; a3 += xv.y * w3.y; a3 += xv.z * w3.z; a3 += xv.w * w3.w;
        }
    }

    // ---- h part: LDS h_prev dot Whh rows ----
    #pragma unroll 8
    for (int k4 = 0; k4 < 64; ++k4) {
        const int k = k4 * 4;
        const float h0v = ht[(k + 0) * 64 + b];
        const float h1v = ht[(k + 1) * 64 + b];
        const float h2v = ht[(k + 2) * 64 + b];
        const float h3v = ht[(k + 3) * 64 + b];
        const float4 w0 = Wh0[k4], w1 = Wh1[k4], w2 = Wh2[k4], w3 = Wh3[k4];
        a0 += h0v * w0.x; a0 += h1v * w0.y; a0 += h2v * w0.z; a0 += h3v * w0.w;
        a1 += h0v * w1.x; a1 += h1v * w1.y; a1 += h2v * w1.z; a1 += h3v * w1.w;
        a2 += h0v * w2.x; a2 += h1v * w2.y; a2 += h2v * w2.z; a2 += h3v * w2.w;
        a3 += h0v * w3.x; a3 += h1v * w3.y; a3 += h2v * w3.z; a3 += h3v * w3.w;
    }

    // ---- cell update (PyTorch gate order i,f,g,o) ----
    const float i_g = 1.0f / (1.0f + expf(-a0));
    const float f_g = 1.0f / (1.0f + expf(-a1));
    const float g_g = tanhf(a2);
    const float o_g = 1.0f / (1.0f + expf(-a3));
    const float c_old = c_prev[b * HH + u];
    const float c_new = f_g * c_old + i_g * g_g;
    const float h_new = o_g * tanhf(c_new);
    cS[b * HH + u] = c_new;
    hs[(size_t)t_emb * BH + b * HH + u] = h_new;
}

// ---------------------------------------------------------------------------
// Emission scores: scores[t,b,s] = hsF[t,b,:].W_lin[s,:256] +
// hsB[t,b,:].W_lin[s,256:] + b_lin[s].  One block per t; 64x64 tile, K=512
// in 4 staged chunks of 128; thread tile 4b x 4s.
// ---------------------------------------------------------------------------
__global__ __launch_bounds__(256) void scores_kernel(
    const float* __restrict__ hsF, const float* __restrict__ hsB,
    const float* __restrict__ W_lin, const float* __restrict__ b_lin,
    float* __restrict__ scores)
{
    __shared__ float As[128 * 64];   // As[k][b]
    __shared__ float Ws[128 * 64];   // Ws[k][s]
    const int t   = blockIdx.x;
    const int tid = threadIdx.x;
    const int bl  = tid & 63;        // staging lane (b or s)
    const int kc  = tid >> 6;        // 0..3
    const int tb  = tid & 15;        // compute: b-tile
    const int ts  = tid >> 4;        // compute: s-tile

    float acc[4][4] = {};

    for (int chunk = 0; chunk < 4; ++chunk) {
        const int koff = chunk * 128;   // position in 512-wide feats
        const float* srcA = (koff < 256) ? (hsF + (size_t)t * BH + koff)
                                         : (hsB + (size_t)t * BH + (koff - 256));
        const float4* srcA4 = (const float4*)srcA;     // row stride 64 f4
        const float4* wl4   = (const float4*)(W_lin + koff); // row stride 128 f4
        #pragma unroll
        for (int it = 0; it < 8; ++it) {
            const int k4 = it * 4 + kc;    // 0..31
            float4 v = srcA4[bl * 64 + k4];
            const int k = k4 * 4;
            As[(k + 0) * 64 + bl] = v.x; As[(k + 1) * 64 + bl] = v.y;
            As[(k + 2) * 64 + bl] = v.z; As[(k + 3) * 64 + bl] = v.w;
            float4 w = wl4[bl * 128 + k4];
            Ws[(k + 0) * 64 + bl] = w.x; Ws[(k + 1) * 64 + bl] = w.y;
            Ws[(k + 2) * 64 + bl] = w.z; Ws[(k + 3) * 64 + bl] = w.w;
        }
        __syncthreads();
        #pragma unroll 4
        for (int k = 0; k < 128; ++k) {
            const float4 av = *(const float4*)&As[k * 64 + tb * 4];
            const float4 bv = *(const float4*)&Ws[k * 64 + ts * 4];
            acc[0][0] += av.x * bv.x; acc[0][1] += av.x * bv.y; acc[0][2] += av.x * bv.z; acc[0][3] += av.x * bv.w;
            acc[1][0] += av.y * bv.x; acc[1][1] += av.y * bv.y; acc[1][2] += av.y * bv.z; acc[1][3] += av.y * bv.w;
            acc[2][0] += av.z * bv.x; acc[2][1] += av.z * bv.y; acc[2][2] += av.z * bv.z; acc[2][3] += av.z * bv.w;
            acc[3][0] += av.w * bv.x; acc[3][1] += av.w * bv.y; acc[3][2] += av.w * bv.z; acc[3][3] += av.w * bv.w;
        }
        __syncthreads();
    }

    #pragma unroll
    for (int i = 0; i < 4; ++i) {
        const int bb = tb * 4 + i;
        #pragma unroll
        for (int j = 0; j < 4; ++j) {
            const int ss = ts * 4 + j;
            scores[(size_t)t * (BB * SS) + bb * SS + ss] = acc[i][j] + b_lin[ss];
        }
    }
}

// ---------------------------------------------------------------------------
// Viterbi forward + backtrace. One block (one wave, 64 threads) per batch b;
// thread = next-state s. Backpointers stay in LDS (511*64 u8). Strict '>'
// comparisons reproduce numpy first-index argmax tie-breaking.
// ---------------------------------------------------------------------------
__global__ __launch_bounds__(64) void viterbi_kernel(
    const float* __restrict__ scores, const float* __restrict__ pairwise,
    const float* __restrict__ start, const float* __restrict__ stop,
    float* __restrict__ out)   // out[0..63] = max_score; out[64 + t*64 + b] = state
{
    __shared__ float pwT[64 * 65];            // pwT[s][p] = pairwise[p][s]
    __shared__ float delta[2][64];
    __shared__ unsigned char bps[511 * 64];   // bps[t-1][s]
    __shared__ float fin[64];

    const int b = blockIdx.x;
    const int s = threadIdx.x;

    for (int p = 0; p < 64; ++p)              // coalesced global, conflict-free LDS
        pwT[s * 65 + p] = pairwise[p * 64 + s];
    delta[0][s] = start[s] + scores[b * SS + s];
    __syncthreads();

    int cur = 0;
    for (int t = 1; t < TT; ++t) {
        const float sc = scores[(size_t)t * (BB * SS) + b * SS + s];
        float best = -1e30f;
        int bp = 0;
        #pragma unroll 8
        for (int p = 0; p < 64; ++p) {
            const float v = delta[cur][p] + pwT[s * 65 + p];  // delta: broadcast
            if (v > best) { best = v; bp = p; }
        }
        delta[cur ^ 1][s] = best + sc;
        bps[(t - 1) * 64 + s] = (unsigned char)bp;
        cur ^= 1;
        __syncthreads();
    }

    fin[s] = delta[cur][s] + stop[s];
    __syncthreads();

    if (s == 0) {
        float m = fin[0];
        int arg = 0;
        for (int p = 1; p < 64; ++p)
            if (fin[p] > m) { m = fin[p]; arg = p; }
        out[b] = m;
        int st = arg;
        out[64 + 511 * 64 + b] = (float)st;
        for (int k = 510; k >= 0; --k) {
            st = bps[k * 64 + st];
            out[64 + k * 64 + b] = (float)st;
        }
    }
}

// ---------------------------------------------------------------------------
extern "C" void kernel_launch(void* const* d_in, const int* in_sizes, int n_in,
                              void* d_out, int out_size, void* d_ws, size_t ws_size,
                              hipStream_t stream)
{
    const int*   obs      = (const int*)d_in[0];
    const float* h0       = (const float*)d_in[1];
    const float* c0       = (const float*)d_in[2];
    const float* embed    = (const float*)d_in[3];
    const float* Wih_f    = (const float*)d_in[4];
    const float* Whh_f    = (const float*)d_in[5];
    const float* bih_f    = (const float*)d_in[6];
    const float* bhh_f    = (const float*)d_in[7];
    const float* Wih_b    = (const float*)d_in[8];
    const float* Whh_b    = (const float*)d_in[9];
    const float* bih_b    = (const float*)d_in[10];
    const float* bhh_b    = (const float*)d_in[11];
    const float* W_lin    = (const float*)d_in[12];
    const float* b_lin    = (const float*)d_in[13];
    const float* pairwise = (const float*)d_in[14];
    const float* start    = (const float*)d_in[15];
    const float* stop     = (const float*)d_in[16];
    (void)in_sizes; (void)n_in; (void)out_size; (void)ws_size;

    // ws layout (floats): hsF | hsB | scores | cF | cB   (~76 MB)
    float* ws     = (float*)d_ws;
    float* hsF    = ws;
    float* hsB    = hsF + (size_t)TT * BH;        // +8388608
    float* scores = hsB + (size_t)TT * BH;        // +8388608
    float* cF     = scores + (size_t)TT * BB * SS; // +2097152
    float* cB     = cF + BH;

    for (int s = 0; s < TT; ++s) {
        lstm_step<<<dim3(64, 2), 256, 0, stream>>>(
            s, obs, embed, Wih_f, Whh_f, bih_f, bhh_f,
            Wih_b, Whh_b, bih_b, bhh_b, h0, c0, hsF, hsB, cF, cB);
    }
    scores_kernel<<<512, 256, 0, stream>>>(hsF, hsB, W_lin, b_lin, scores);
    viterbi_kernel<<<64, 64, 0, stream>>>(scores, pairwise, start, stop, (float*)d_out);
}

// Round 2
// 11633.350 us; speedup vs baseline: 1.0322x; 1.0322x over previous
//
#include <hip/hip_runtime.h>
#include <math.h>

// Problem constants
constexpr int TT = 512;   // sequence length
constexpr int BB = 64;    // batch
constexpr int EE = 256;   // embed dim
constexpr int HH = 256;   // hidden
constexpr int SS = 64;    // states
constexpr int BH = BB * HH;       // 16384
constexpr int KB16 = HH * BB;     // floats per t-slice of transposed arrays (16384)

// ---------------------------------------------------------------------------
// embT[t][k][b] = embed[obs[t][b]][k]  (transposed embedding sequence)
// ---------------------------------------------------------------------------
__global__ __launch_bounds__(256) void embT_prep(
    const int* __restrict__ obs, const float* __restrict__ embed,
    float* __restrict__ embT)
{
    const int t   = blockIdx.x;
    const int tid = threadIdx.x;
    const int b   = tid & 63;
    const int kc  = tid >> 6;                       // 0..3
    const int tok = obs[t * BB + b];
    const float4* er = (const float4*)(embed + (size_t)tok * EE);
    float* dst = embT + (size_t)t * KB16;
    #pragma unroll
    for (int i = 0; i < 16; ++i) {
        const int k4 = kc * 16 + i;
        float4 v = er[k4];
        const int k = k4 * 4;
        dst[(k + 0) * 64 + b] = v.x;
        dst[(k + 1) * 64 + b] = v.y;
        dst[(k + 2) * 64 + b] = v.z;
        dst[(k + 3) * 64 + b] = v.w;
    }
}

// ---------------------------------------------------------------------------
// Persistent BiLSTM recurrence. Grid 256 = 2 dirs x 128 ublocks; 512 threads.
// Block owns units {u0,u0+1}; thread (b = tid&63, w = tid>>6 = K-chunk of 32).
// Per step: stage x_t (memcpy into LDS), x-dots; stage h_prev, h-dots;
// partials via LDS; 128 cell threads update c (registers) and store h
// transposed to hsT[t][u][b]; per-direction global barrier (monotone atomic
// counter, device-scope; safe: 64KB LDS => 2 blocks/CU capacity => all 256
// blocks co-resident for a 256-block grid).
// ---------------------------------------------------------------------------
__global__ __launch_bounds__(512) void lstm_persist(
    const float* __restrict__ embT,
    const float* __restrict__ Wih_f, const float* __restrict__ Whh_f,
    const float* __restrict__ bih_f, const float* __restrict__ bhh_f,
    const float* __restrict__ Wih_b, const float* __restrict__ Whh_b,
    const float* __restrict__ bih_b, const float* __restrict__ bhh_b,
    const float* __restrict__ h0, const float* __restrict__ c0,
    float* __restrict__ hsTf, float* __restrict__ hsTb,
    unsigned int* __restrict__ ctr)
{
    __shared__ float buf[16384];   // 64 KB: x / h staging, then partial scratch
    const int tid  = threadIdx.x;
    const int b    = tid & 63;
    const int w    = tid >> 6;     // 0..7 K-chunk index
    const int bx   = blockIdx.x;
    const int dir  = bx & 1;
    const int ublk = bx >> 1;      // 0..127
    const int u0   = ublk * 2;

    const float* Wih = dir ? Wih_b : Wih_f;
    const float* Whh = dir ? Whh_b : Whh_f;
    const float* bih = dir ? bih_b : bih_f;
    const float* bhh = dir ? bhh_b : bhh_f;
    float* hsT = dir ? hsTb : hsTf;
    unsigned int* myctr = ctr + dir * 32;   // 128 B apart

    // rows for the 8 dots: r -> gate = r>>1, unit = u0 + (r&1)
    const int row0 = 0 * 256 + u0, row1 = 0 * 256 + u0 + 1;
    const int row2 = 1 * 256 + u0, row3 = 1 * 256 + u0 + 1;
    const int row4 = 2 * 256 + u0, row5 = 2 * 256 + u0 + 1;
    const int row6 = 3 * 256 + u0, row7 = 3 * 256 + u0 + 1;

    // persistent cell state (tid<128: uo = tid>>6, u = u0+uo)
    float c_reg = 0.0f;
    if (tid < 128) {
        const int uo = tid >> 6;
        c_reg = c0[dir * BH + b * HH + (u0 + uo)];
    }

    const int kbase = w * 32;
    float4* buf4 = (float4*)buf;
    const float* bufp = buf + kbase * 64 + b;   // dot-read base

    for (int step = 0; step < TT; ++step) {
        const int t_emb = dir ? (TT - 1 - step) : step;

        // ---- stage x_t (straight 64 KB copy) ----
        {
            const float4* src = (const float4*)(embT + (size_t)t_emb * KB16);
            #pragma unroll
            for (int i = 0; i < 8; ++i) buf4[tid + i * 512] = src[tid + i * 512];
        }
        __syncthreads();

        float acc[8];
        #pragma unroll
        for (int r = 0; r < 8; ++r) acc[r] = 0.0f;

        // ---- x dots (K-chunk of 32) ----
        {
            const float* w0 = Wih + row0 * EE + kbase;
            const float* w1 = Wih + row1 * EE + kbase;
            const float* w2 = Wih + row2 * EE + kbase;
            const float* w3 = Wih + row3 * EE + kbase;
            const float* w4 = Wih + row4 * EE + kbase;
            const float* w5 = Wih + row5 * EE + kbase;
            const float* w6 = Wih + row6 * EE + kbase;
            const float* w7 = Wih + row7 * EE + kbase;
            #pragma unroll 8
            for (int k = 0; k < 32; ++k) {
                const float x = bufp[k * 64];
                acc[0] = fmaf(x, w0[k], acc[0]);
                acc[1] = fmaf(x, w1[k], acc[1]);
                acc[2] = fmaf(x, w2[k], acc[2]);
                acc[3] = fmaf(x, w3[k], acc[3]);
                acc[4] = fmaf(x, w4[k], acc[4]);
                acc[5] = fmaf(x, w5[k], acc[5]);
                acc[6] = fmaf(x, w6[k], acc[6]);
                acc[7] = fmaf(x, w7[k], acc[7]);
            }
        }
        __syncthreads();   // before overwriting buf with h

        // ---- stage h_prev ----
        if (step == 0) {
            // h0 is [dir][b][k]: transpose-stage
            const float4* src = (const float4*)(h0 + dir * BH);
            #pragma unroll
            for (int i = 0; i < 8; ++i) {
                const int idx = tid + i * 512;      // f4 index
                float4 v = src[idx];
                const int bb = idx >> 6;
                const int k  = (idx & 63) * 4;
                buf[(k + 0) * 64 + bb] = v.x;
                buf[(k + 1) * 64 + bb] = v.y;
                buf[(k + 2) * 64 + bb] = v.z;
                buf[(k + 3) * 64 + bb] = v.w;
            }
        } else {
            const int t_prev = dir ? (t_emb + 1) : (t_emb - 1);
            const float4* src = (const float4*)(hsT + (size_t)t_prev * KB16);
            #pragma unroll
            for (int i = 0; i < 8; ++i) buf4[tid + i * 512] = src[tid + i * 512];
        }
        __syncthreads();

        // ---- h dots ----
        {
            const float* w0 = Whh + row0 * HH + kbase;
            const float* w1 = Whh + row1 * HH + kbase;
            const float* w2 = Whh + row2 * HH + kbase;
            const float* w3 = Whh + row3 * HH + kbase;
            const float* w4 = Whh + row4 * HH + kbase;
            const float* w5 = Whh + row5 * HH + kbase;
            const float* w6 = Whh + row6 * HH + kbase;
            const float* w7 = Whh + row7 * HH + kbase;
            #pragma unroll 8
            for (int k = 0; k < 32; ++k) {
                const float x = bufp[k * 64];
                acc[0] = fmaf(x, w0[k], acc[0]);
                acc[1] = fmaf(x, w1[k], acc[1]);
                acc[2] = fmaf(x, w2[k], acc[2]);
                acc[3] = fmaf(x, w3[k], acc[3]);
                acc[4] = fmaf(x, w4[k], acc[4]);
                acc[5] = fmaf(x, w5[k], acc[5]);
                acc[6] = fmaf(x, w6[k], acc[6]);
                acc[7] = fmaf(x, w7[k], acc[7]);
            }
        }
        __syncthreads();   // before overwriting buf with partials

        // ---- exchange partials: scr[w][dot], dot = r*64 + b ----
        #pragma unroll
        for (int r = 0; r < 8; ++r) buf[w * 512 + r * 64 + b] = acc[r];
        __syncthreads();

        // ---- cell update (128 threads: b, uo) ----
        if (tid < 128) {
            const int uo = tid >> 6;
            const int u  = u0 + uo;
            float p[4];
            #pragma unroll
            for (int g = 0; g < 4; ++g) {
                const int d = (g * 2 + uo) * 64 + b;
                float s = 0.0f;
                #pragma unroll
                for (int ww = 0; ww < 8; ++ww) s += buf[ww * 512 + d];
                const int row = g * 256 + u;
                p[g] = s + bih[row] + bhh[row];
            }
            const float ig = 1.0f / (1.0f + expf(-p[0]));
            const float fg = 1.0f / (1.0f + expf(-p[1]));
            const float gg = tanhf(p[2]);
            const float og = 1.0f / (1.0f + expf(-p[3]));
            c_reg = fg * c_reg + ig * gg;
            const float h = og * tanhf(c_reg);
            hsT[(size_t)t_emb * KB16 + u * 64 + b] = h;   // coalesced
        }
        __syncthreads();   // all waves' stores drained (vmcnt) before arrive

        // ---- per-direction grid barrier (skip after last step) ----
        if (step < TT - 1) {
            if (tid == 0) {
                __threadfence();                       // release h stores
                atomicAdd(myctr, 1u);
                const unsigned tgt = 128u * (unsigned)(step + 1);
                while (__hip_atomic_load(myctr, __ATOMIC_RELAXED,
                                         __HIP_MEMORY_SCOPE_AGENT) < tgt)
                    __builtin_amdgcn_s_sleep(2);
                __threadfence();                       // acquire
            }
            __syncthreads();
        }
    }
}

// ---------------------------------------------------------------------------
// scores[t,b,s] = sum_k hsTf[t][k][b]*W_lin[s][k] + hsTb[t][k][b]*W_lin[s][256+k]
//                 + b_lin[s].  One block per t.
// ---------------------------------------------------------------------------
__global__ __launch_bounds__(256) void scores_kernel(
    const float* __restrict__ hsTf, const float* __restrict__ hsTb,
    const float* __restrict__ W_lin, const float* __restrict__ b_lin,
    float* __restrict__ scores)
{
    __shared__ float As[128 * 64];   // As[k][b]
    __shared__ float Ws[128 * 64];   // Ws[k][s]
    const int t   = blockIdx.x;
    const int tid = threadIdx.x;
    const int bl  = tid & 63;
    const int kc  = tid >> 6;        // 0..3
    const int tb  = tid & 15;
    const int ts  = tid >> 4;

    float acc[4][4] = {};

    for (int chunk = 0; chunk < 4; ++chunk) {
        const int koff = chunk * 128;
        const float* srcA = (koff < 256)
            ? (hsTf + (size_t)t * KB16 + (size_t)koff * 64)
            : (hsTb + (size_t)t * KB16 + (size_t)(koff - 256) * 64);
        // A-stage: straight 32 KB copy (already [k][b])
        const float4* sA4 = (const float4*)srcA;
        float4* As4 = (float4*)As;
        #pragma unroll
        for (int i = 0; i < 8; ++i) As4[tid + i * 256] = sA4[tid + i * 256];
        // W-stage: transpose W_lin[s][koff+k] -> Ws[k][s]
        const float4* wl4 = (const float4*)(W_lin + koff);  // row pitch 128 f4
        #pragma unroll
        for (int it = 0; it < 8; ++it) {
            const int k4 = it * 4 + kc;
            float4 wv = wl4[bl * 128 + k4];
            const int k = k4 * 4;
            Ws[(k + 0) * 64 + bl] = wv.x; Ws[(k + 1) * 64 + bl] = wv.y;
            Ws[(k + 2) * 64 + bl] = wv.z; Ws[(k + 3) * 64 + bl] = wv.w;
        }
        __syncthreads();
        #pragma unroll 4
        for (int k = 0; k < 128; ++k) {
            const float4 av = *(const float4*)&As[k * 64 + tb * 4];
            const float4 bv = *(const float4*)&Ws[k * 64 + ts * 4];
            acc[0][0] += av.x * bv.x; acc[0][1] += av.x * bv.y; acc[0][2] += av.x * bv.z; acc[0][3] += av.x * bv.w;
            acc[1][0] += av.y * bv.x; acc[1][1] += av.y * bv.y; acc[1][2] += av.y * bv.z; acc[1][3] += av.y * bv.w;
            acc[2][0] += av.z * bv.x; acc[2][1] += av.z * bv.y; acc[2][2] += av.z * bv.z; acc[2][3] += av.z * bv.w;
            acc[3][0] += av.w * bv.x; acc[3][1] += av.w * bv.y; acc[3][2] += av.w * bv.z; acc[3][3] += av.w * bv.w;
        }
        __syncthreads();
    }

    #pragma unroll
    for (int i = 0; i < 4; ++i) {
        const int bb = tb * 4 + i;
        #pragma unroll
        for (int j = 0; j < 4; ++j) {
            const int ss = ts * 4 + j;
            scores[(size_t)t * (BB * SS) + bb * SS + ss] = acc[i][j] + b_lin[ss];
        }
    }
}

// ---------------------------------------------------------------------------
// Viterbi forward + backtrace. One block (one wave) per batch b.
// ---------------------------------------------------------------------------
__global__ __launch_bounds__(64) void viterbi_kernel(
    const float* __restrict__ scores, const float* __restrict__ pairwise,
    const float* __restrict__ start, const float* __restrict__ stop,
    float* __restrict__ out)
{
    __shared__ float pwT[64 * 65];            // pwT[s][p] = pairwise[p][s]
    __shared__ float delta[2][64];
    __shared__ unsigned char bps[511 * 64];
    __shared__ float fin[64];

    const int b = blockIdx.x;
    const int s = threadIdx.x;

    for (int p = 0; p < 64; ++p)
        pwT[s * 65 + p] = pairwise[p * 64 + s];
    delta[0][s] = start[s] + scores[b * SS + s];
    __syncthreads();

    int cur = 0;
    for (int t = 1; t < TT; ++t) {
        const float sc = scores[(size_t)t * (BB * SS) + b * SS + s];
        float best = -1e30f;
        int bp = 0;
        #pragma unroll 8
        for (int p = 0; p < 64; ++p) {
            const float v = delta[cur][p] + pwT[s * 65 + p];
            if (v > best) { best = v; bp = p; }
        }
        delta[cur ^ 1][s] = best + sc;
        bps[(t - 1) * 64 + s] = (unsigned char)bp;
        cur ^= 1;
        __syncthreads();
    }

    fin[s] = delta[cur][s] + stop[s];
    __syncthreads();

    if (s == 0) {
        float m = fin[0];
        int arg = 0;
        for (int p = 1; p < 64; ++p)
            if (fin[p] > m) { m = fin[p]; arg = p; }
        out[b] = m;
        int st = arg;
        out[64 + 511 * 64 + b] = (float)st;
        for (int k = 510; k >= 0; --k) {
            st = bps[k * 64 + st];
            out[64 + k * 64 + b] = (float)st;
        }
    }
}

// ---------------------------------------------------------------------------
extern "C" void kernel_launch(void* const* d_in, const int* in_sizes, int n_in,
                              void* d_out, int out_size, void* d_ws, size_t ws_size,
                              hipStream_t stream)
{
    const int*   obs      = (const int*)d_in[0];
    const float* h0       = (const float*)d_in[1];
    const float* c0       = (const float*)d_in[2];
    const float* embed    = (const float*)d_in[3];
    const float* Wih_f    = (const float*)d_in[4];
    const float* Whh_f    = (const float*)d_in[5];
    const float* bih_f    = (const float*)d_in[6];
    const float* bhh_f    = (const float*)d_in[7];
    const float* Wih_b    = (const float*)d_in[8];
    const float* Whh_b    = (const float*)d_in[9];
    const float* bih_b    = (const float*)d_in[10];
    const float* bhh_b    = (const float*)d_in[11];
    const float* W_lin    = (const float*)d_in[12];
    const float* b_lin    = (const float*)d_in[13];
    const float* pairwise = (const float*)d_in[14];
    const float* start    = (const float*)d_in[15];
    const float* stop     = (const float*)d_in[16];
    (void)in_sizes; (void)n_in; (void)out_size; (void)ws_size;

    // ws layout (floats): embT | hsTf | hsTb | scores | ctr   (~109 MB)
    float* ws     = (float*)d_ws;
    float* embT   = ws;
    float* hsTf   = embT + (size_t)TT * KB16;
    float* hsTb   = hsTf + (size_t)TT * KB16;
    float* scores = hsTb + (size_t)TT * KB16;
    unsigned int* ctr = (unsigned int*)(scores + (size_t)TT * BB * SS);

    hipMemsetAsync(ctr, 0, 256, stream);
    embT_prep<<<512, 256, 0, stream>>>(obs, embed, embT);
    lstm_persist<<<256, 512, 0, stream>>>(
        embT, Wih_f, Whh_f, bih_f, bhh_f, Wih_b, Whh_b, bih_b, bhh_b,
        h0, c0, hsTf, hsTb, ctr);
    scores_kernel<<<512, 256, 0, stream>>>(hsTf, hsTb, W_lin, b_lin, scores);
    viterbi_kernel<<<64, 64, 0, stream>>>(scores, pairwise, start, stop, (float*)d_out);
}

// Round 3
// 3875.591 us; speedup vs baseline: 3.0983x; 3.0017x over previous
//
#include <hip/hip_runtime.h>
#include <math.h>

// Problem constants
constexpr int TT = 512;   // sequence length
constexpr int BB = 64;    // batch
constexpr int EE = 256;   // embed dim
constexpr int HH = 256;   // hidden
constexpr int SS = 64;    // states
constexpr int BH = BB * HH;       // 16384
constexpr int KB16 = HH * BB;     // floats per t-slice of transposed arrays (16384)

// ---------------------------------------------------------------------------
// embT[t][k][b] = embed[obs[t][b]][k]  (transposed embedding sequence)
// ---------------------------------------------------------------------------
__global__ __launch_bounds__(256) void embT_prep(
    const int* __restrict__ obs, const float* __restrict__ embed,
    float* __restrict__ embT)
{
    const int t   = blockIdx.x;
    const int tid = threadIdx.x;
    const int b   = tid & 63;
    const int kc  = tid >> 6;                       // 0..3
    const int tok = obs[t * BB + b];
    const float4* er = (const float4*)(embed + (size_t)tok * EE);
    float* dst = embT + (size_t)t * KB16;
    #pragma unroll
    for (int i = 0; i < 16; ++i) {
        const int k4 = kc * 16 + i;
        float4 v = er[k4];
        const int k = k4 * 4;
        dst[(k + 0) * 64 + b] = v.x;
        dst[(k + 1) * 64 + b] = v.y;
        dst[(k + 2) * 64 + b] = v.z;
        dst[(k + 3) * 64 + b] = v.w;
    }
}

// ---------------------------------------------------------------------------
// Persistent BiLSTM recurrence, fence-free.
// Grid 256 = 2 dirs x 128 ublocks; 512 threads (8 waves), 2 blocks/CU.
// Thread (b = tid&63, w = tid>>6): owns K-chunk [w*32, w*32+32) of the 8
// gate-rows {g*256+u0, g*256+u0+1}. x-part read directly from embT (cached,
// L2-hot). h-part read with sc0+sc1 (coherence point) — no fences, no L2
// invalidation, weights stay cache-hot for all 512 steps. Per-block step
// stamp flags (plain sc1 stores) replace the contended atomic counter.
// Deadlock-safe: 16 KB LDS, 256 blocks trivially co-resident.
// ---------------------------------------------------------------------------
__global__ __launch_bounds__(512, 4) void lstm_persist(
    const float* __restrict__ embT,
    const float* __restrict__ Wih_f, const float* __restrict__ Whh_f,
    const float* __restrict__ bih_f, const float* __restrict__ bhh_f,
    const float* __restrict__ Wih_b, const float* __restrict__ Whh_b,
    const float* __restrict__ bih_b, const float* __restrict__ bhh_b,
    const float* __restrict__ h0, const float* __restrict__ c0,
    float* __restrict__ hsTf, float* __restrict__ hsTb,
    unsigned int* __restrict__ flags)
{
    __shared__ float buf[4096];    // 16 KB: partial exchange only
    const int tid  = threadIdx.x;
    const int b    = tid & 63;
    const int w    = tid >> 6;     // 0..7 K-chunk index
    const int bx   = blockIdx.x;
    const int dir  = bx & 1;
    const int ublk = bx >> 1;      // 0..127
    const int u0   = ublk * 2;

    const float* Wih = dir ? Wih_b : Wih_f;
    const float* Whh = dir ? Whh_b : Whh_f;
    const float* bih = dir ? bih_b : bih_f;
    const float* bhh = dir ? bhh_b : bhh_f;
    float* hsT = dir ? hsTb : hsTf;
    unsigned int* dirflags = flags + dir * 128;

    const int kbase = w * 32;
    const int kb_s  = __builtin_amdgcn_readfirstlane(kbase);

    // 8 gate-row weight bases (wave-uniform -> scalar loads via K$)
    const float* Wx0 = Wih + (size_t)(0 * 256 + u0    ) * EE + kb_s;
    const float* Wx1 = Wih + (size_t)(0 * 256 + u0 + 1) * EE + kb_s;
    const float* Wx2 = Wih + (size_t)(1 * 256 + u0    ) * EE + kb_s;
    const float* Wx3 = Wih + (size_t)(1 * 256 + u0 + 1) * EE + kb_s;
    const float* Wx4 = Wih + (size_t)(2 * 256 + u0    ) * EE + kb_s;
    const float* Wx5 = Wih + (size_t)(2 * 256 + u0 + 1) * EE + kb_s;
    const float* Wx6 = Wih + (size_t)(3 * 256 + u0    ) * EE + kb_s;
    const float* Wx7 = Wih + (size_t)(3 * 256 + u0 + 1) * EE + kb_s;
    const float* Wh0 = Whh + (size_t)(0 * 256 + u0    ) * HH + kb_s;
    const float* Wh1 = Whh + (size_t)(0 * 256 + u0 + 1) * HH + kb_s;
    const float* Wh2 = Whh + (size_t)(1 * 256 + u0    ) * HH + kb_s;
    const float* Wh3 = Whh + (size_t)(1 * 256 + u0 + 1) * HH + kb_s;
    const float* Wh4 = Whh + (size_t)(2 * 256 + u0    ) * HH + kb_s;
    const float* Wh5 = Whh + (size_t)(2 * 256 + u0 + 1) * HH + kb_s;
    const float* Wh6 = Whh + (size_t)(3 * 256 + u0    ) * HH + kb_s;
    const float* Wh7 = Whh + (size_t)(3 * 256 + u0 + 1) * HH + kb_s;

    // persistent cell state + biases (tid<128: uo = tid>>6, unit u0+uo)
    float c_reg = 0.0f;
    float bias0 = 0.f, bias1 = 0.f, bias2 = 0.f, bias3 = 0.f;
    if (tid < 128) {
        const int uo = tid >> 6;
        const int u  = u0 + uo;
        c_reg = c0[dir * BH + b * HH + u];
        bias0 = bih[0 * 256 + u] + bhh[0 * 256 + u];
        bias1 = bih[1 * 256 + u] + bhh[1 * 256 + u];
        bias2 = bih[2 * 256 + u] + bhh[2 * 256 + u];
        bias3 = bih[3 * 256 + u] + bhh[3 * 256 + u];
    }

    for (int step = 0; step < TT; ++step) {
        const int t_emb = dir ? (TT - 1 - step) : step;

        float acc0 = 0.f, acc1 = 0.f, acc2 = 0.f, acc3 = 0.f;
        float acc4 = 0.f, acc5 = 0.f, acc6 = 0.f, acc7 = 0.f;

        // ---- x dots: direct cached loads from embT (no h dependency) ----
        {
            const float* xs = embT + (size_t)t_emb * KB16 + kbase * 64 + b;
            #pragma unroll 8
            for (int k = 0; k < 32; ++k) {
                const float x = xs[k * 64];
                acc0 = fmaf(x, Wx0[k], acc0);
                acc1 = fmaf(x, Wx1[k], acc1);
                acc2 = fmaf(x, Wx2[k], acc2);
                acc3 = fmaf(x, Wx3[k], acc3);
                acc4 = fmaf(x, Wx4[k], acc4);
                acc5 = fmaf(x, Wx5[k], acc5);
                acc6 = fmaf(x, Wx6[k], acc6);
                acc7 = fmaf(x, Wx7[k], acc7);
            }
        }

        // ---- wait for producers of h(step-1): wave 0 polls 128 flags ----
        if (step > 0) {
            if (tid < 64) {
                const unsigned tgt = (unsigned)step;
                const unsigned int* fp = dirflags + tid * 2;
                for (;;) {
                    uint2 fv;
                    asm volatile("global_load_dwordx2 %0, %1, off sc0 sc1"
                                 : "=v"(fv) : "v"(fp));
                    asm volatile("s_waitcnt vmcnt(0)" ::: "memory");
                    if (__all(fv.x >= tgt && fv.y >= tgt)) break;
                    __builtin_amdgcn_s_sleep(1);
                }
            }
            __syncthreads();
        }

        // ---- h values: 32 floats per thread ----
        float hv[32];
        if (step == 0) {
            const float* hp = h0 + dir * BH + b * HH + kbase;  // contiguous
            #pragma unroll
            for (int k = 0; k < 32; ++k) hv[k] = hp[k];
        } else {
            const int t_prev = dir ? (t_emb + 1) : (t_emb - 1);
            const float* hsrc = hsT + (size_t)t_prev * KB16 + kbase * 64 + b;
            #pragma unroll
            for (int k = 0; k < 32; ++k) {
                asm volatile("global_load_dword %0, %1, off sc0 sc1"
                             : "=v"(hv[k]) : "v"(hsrc + k * 64));
            }
            asm volatile("s_waitcnt vmcnt(0)" ::: "memory");
        }

        // ---- h dots ----
        #pragma unroll 8
        for (int k = 0; k < 32; ++k) {
            const float h = hv[k];
            acc0 = fmaf(h, Wh0[k], acc0);
            acc1 = fmaf(h, Wh1[k], acc1);
            acc2 = fmaf(h, Wh2[k], acc2);
            acc3 = fmaf(h, Wh3[k], acc3);
            acc4 = fmaf(h, Wh4[k], acc4);
            acc5 = fmaf(h, Wh5[k], acc5);
            acc6 = fmaf(h, Wh6[k], acc6);
            acc7 = fmaf(h, Wh7[k], acc7);
        }

        // ---- exchange partials: buf[w][dot], dot = r*64 + b ----
        buf[w * 512 + 0 * 64 + b] = acc0;
        buf[w * 512 + 1 * 64 + b] = acc1;
        buf[w * 512 + 2 * 64 + b] = acc2;
        buf[w * 512 + 3 * 64 + b] = acc3;
        buf[w * 512 + 4 * 64 + b] = acc4;
        buf[w * 512 + 5 * 64 + b] = acc5;
        buf[w * 512 + 6 * 64 + b] = acc6;
        buf[w * 512 + 7 * 64 + b] = acc7;
        __syncthreads();

        // ---- cell update (128 threads: b, uo) ----
        if (tid < 128) {
            const int uo = tid >> 6;
            const int u  = u0 + uo;
            float p0 = bias0, p1 = bias1, p2 = bias2, p3 = bias3;
            #pragma unroll
            for (int ww = 0; ww < 8; ++ww) {
                p0 += buf[ww * 512 + (0 * 2 + uo) * 64 + b];
                p1 += buf[ww * 512 + (1 * 2 + uo) * 64 + b];
                p2 += buf[ww * 512 + (2 * 2 + uo) * 64 + b];
                p3 += buf[ww * 512 + (3 * 2 + uo) * 64 + b];
            }
            const float ig = 1.0f / (1.0f + expf(-p0));
            const float fg = 1.0f / (1.0f + expf(-p1));
            const float gg = tanhf(p2);
            const float og = 1.0f / (1.0f + expf(-p3));
            c_reg = fg * c_reg + ig * gg;
            const float h = og * tanhf(c_reg);
            float* dst = hsT + (size_t)t_emb * KB16 + u * 64 + b;
            asm volatile("global_store_dword %0, %1, off sc0 sc1"
                         :: "v"(dst), "v"(h) : "memory");
        }
        asm volatile("s_waitcnt vmcnt(0)" ::: "memory");
        __syncthreads();   // all h stores at coherence point before flag

        if (step < TT - 1 && tid == 0) {
            const unsigned val = (unsigned)(step + 1);
            unsigned int* fdst = dirflags + ublk;
            asm volatile("global_store_dword %0, %1, off sc0 sc1"
                         :: "v"(fdst), "v"(val) : "memory");
        }
    }
}

// ---------------------------------------------------------------------------
// scores[t,b,s] = sum_k hsTf[t][k][b]*W_lin[s][k] + hsTb[t][k][b]*W_lin[s][256+k]
//                 + b_lin[s].  One block per t.
// ---------------------------------------------------------------------------
__global__ __launch_bounds__(256) void scores_kernel(
    const float* __restrict__ hsTf, const float* __restrict__ hsTb,
    const float* __restrict__ W_lin, const float* __restrict__ b_lin,
    float* __restrict__ scores)
{
    __shared__ float As[128 * 64];   // As[k][b]
    __shared__ float Ws[128 * 64];   // Ws[k][s]
    const int t   = blockIdx.x;
    const int tid = threadIdx.x;
    const int bl  = tid & 63;
    const int kc  = tid >> 6;        // 0..3
    const int tb  = tid & 15;
    const int ts  = tid >> 4;

    float acc[4][4] = {};

    for (int chunk = 0; chunk < 4; ++chunk) {
        const int koff = chunk * 128;
        const float* srcA = (koff < 256)
            ? (hsTf + (size_t)t * KB16 + (size_t)koff * 64)
            : (hsTb + (size_t)t * KB16 + (size_t)(koff - 256) * 64);
        const float4* sA4 = (const float4*)srcA;
        float4* As4 = (float4*)As;
        #pragma unroll
        for (int i = 0; i < 8; ++i) As4[tid + i * 256] = sA4[tid + i * 256];
        const float4* wl4 = (const float4*)(W_lin + koff);  // row pitch 128 f4
        #pragma unroll
        for (int it = 0; it < 8; ++it) {
            const int k4 = it * 4 + kc;
            float4 wv = wl4[bl * 128 + k4];
            const int k = k4 * 4;
            Ws[(k + 0) * 64 + bl] = wv.x; Ws[(k + 1) * 64 + bl] = wv.y;
            Ws[(k + 2) * 64 + bl] = wv.z; Ws[(k + 3) * 64 + bl] = wv.w;
        }
        __syncthreads();
        #pragma unroll 4
        for (int k = 0; k < 128; ++k) {
            const float4 av = *(const float4*)&As[k * 64 + tb * 4];
            const float4 bv = *(const float4*)&Ws[k * 64 + ts * 4];
            acc[0][0] += av.x * bv.x; acc[0][1] += av.x * bv.y; acc[0][2] += av.x * bv.z; acc[0][3] += av.x * bv.w;
            acc[1][0] += av.y * bv.x; acc[1][1] += av.y * bv.y; acc[1][2] += av.y * bv.z; acc[1][3] += av.y * bv.w;
            acc[2][0] += av.z * bv.x; acc[2][1] += av.z * bv.y; acc[2][2] += av.z * bv.z; acc[2][3] += av.z * bv.w;
            acc[3][0] += av.w * bv.x; acc[3][1] += av.w * bv.y; acc[3][2] += av.w * bv.z; acc[3][3] += av.w * bv.w;
        }
        __syncthreads();
    }

    #pragma unroll
    for (int i = 0; i < 4; ++i) {
        const int bb = tb * 4 + i;
        #pragma unroll
        for (int j = 0; j < 4; ++j) {
            const int ss = ts * 4 + j;
            scores[(size_t)t * (BB * SS) + bb * SS + ss] = acc[i][j] + b_lin[ss];
        }
    }
}

// ---------------------------------------------------------------------------
// Viterbi forward + backtrace. One block (one wave) per batch b.
// ---------------------------------------------------------------------------
__global__ __launch_bounds__(64) void viterbi_kernel(
    const float* __restrict__ scores, const float* __restrict__ pairwise,
    const float* __restrict__ start, const float* __restrict__ stop,
    float* __restrict__ out)
{
    __shared__ float pwT[64 * 65];            // pwT[s][p] = pairwise[p][s]
    __shared__ float delta[2][64];
    __shared__ unsigned char bps[511 * 64];
    __shared__ float fin[64];

    const int b = blockIdx.x;
    const int s = threadIdx.x;

    for (int p = 0; p < 64; ++p)
        pwT[s * 65 + p] = pairwise[p * 64 + s];
    delta[0][s] = start[s] + scores[b * SS + s];
    __syncthreads();

    int cur = 0;
    for (int t = 1; t < TT; ++t) {
        const float sc = scores[(size_t)t * (BB * SS) + b * SS + s];
        float best = -1e30f;
        int bp = 0;
        #pragma unroll 8
        for (int p = 0; p < 64; ++p) {
            const float v = delta[cur][p] + pwT[s * 65 + p];
            if (v > best) { best = v; bp = p; }
        }
        delta[cur ^ 1][s] = best + sc;
        bps[(t - 1) * 64 + s] = (unsigned char)bp;
        cur ^= 1;
        __syncthreads();
    }

    fin[s] = delta[cur][s] + stop[s];
    __syncthreads();

    if (s == 0) {
        float m = fin[0];
        int arg = 0;
        for (int p = 1; p < 64; ++p)
            if (fin[p] > m) { m = fin[p]; arg = p; }
        out[b] = m;
        int st = arg;
        out[64 + 511 * 64 + b] = (float)st;
        for (int k = 510; k >= 0; --k) {
            st = bps[k * 64 + st];
            out[64 + k * 64 + b] = (float)st;
        }
    }
}

// ---------------------------------------------------------------------------
extern "C" void kernel_launch(void* const* d_in, const int* in_sizes, int n_in,
                              void* d_out, int out_size, void* d_ws, size_t ws_size,
                              hipStream_t stream)
{
    const int*   obs      = (const int*)d_in[0];
    const float* h0       = (const float*)d_in[1];
    const float* c0       = (const float*)d_in[2];
    const float* embed    = (const float*)d_in[3];
    const float* Wih_f    = (const float*)d_in[4];
    const float* Whh_f    = (const float*)d_in[5];
    const float* bih_f    = (const float*)d_in[6];
    const float* bhh_f    = (const float*)d_in[7];
    const float* Wih_b    = (const float*)d_in[8];
    const float* Whh_b    = (const float*)d_in[9];
    const float* bih_b    = (const float*)d_in[10];
    const float* bhh_b    = (const float*)d_in[11];
    const float* W_lin    = (const float*)d_in[12];
    const float* b_lin    = (const float*)d_in[13];
    const float* pairwise = (const float*)d_in[14];
    const float* start    = (const float*)d_in[15];
    const float* stop     = (const float*)d_in[16];
    (void)in_sizes; (void)n_in; (void)out_size; (void)ws_size;

    // ws layout (floats): embT | hsTf | hsTb | scores | flags   (~104 MB)
    float* ws     = (float*)d_ws;
    float* embT   = ws;
    float* hsTf   = embT + (size_t)TT * KB16;
    float* hsTb   = hsTf + (size_t)TT * KB16;
    float* scores = hsTb + (size_t)TT * KB16;
    unsigned int* flags = (unsigned int*)(scores + (size_t)TT * BB * SS);

    hipMemsetAsync(flags, 0, 1024, stream);
    embT_prep<<<512, 256, 0, stream>>>(obs, embed, embT);
    lstm_persist<<<256, 512, 0, stream>>>(
        embT, Wih_f, Whh_f, bih_f, bhh_f, Wih_b, Whh_b, bih_b, bhh_b,
        h0, c0, hsTf, hsTb, flags);
    scores_kernel<<<512, 256, 0, stream>>>(hsTf, hsTb, W_lin, b_lin, scores);
    viterbi_kernel<<<64, 64, 0, stream>>>(scores, pairwise, start, stop, (float*)d_out);
}

// Round 4
// 3067.819 us; speedup vs baseline: 3.9140x; 1.2633x over previous
//
#include <hip/hip_runtime.h>
#include <math.h>

// Problem constants
constexpr int TT = 512;   // sequence length
constexpr int BB = 64;    // batch
constexpr int EE = 256;   // embed dim
constexpr int HH = 256;   // hidden
constexpr int SS = 64;    // states
constexpr int BH = BB * HH;       // 16384
constexpr int KB16 = HH * BB;     // floats per t-slice of transposed arrays (16384)

// ---------------------------------------------------------------------------
// embT[t][k][b] = embed[obs[t][b]][k]  (transposed embedding sequence)
// ---------------------------------------------------------------------------
__global__ __launch_bounds__(256) void embT_prep(
    const int* __restrict__ obs, const float* __restrict__ embed,
    float* __restrict__ embT)
{
    const int t   = blockIdx.x;
    const int tid = threadIdx.x;
    const int b   = tid & 63;
    const int kc  = tid >> 6;                       // 0..3
    const int tok = obs[t * BB + b];
    const float4* er = (const float4*)(embed + (size_t)tok * EE);
    float* dst = embT + (size_t)t * KB16;
    #pragma unroll
    for (int i = 0; i < 16; ++i) {
        const int k4 = kc * 16 + i;
        float4 v = er[k4];
        const int k = k4 * 4;
        dst[(k + 0) * 64 + b] = v.x;
        dst[(k + 1) * 64 + b] = v.y;
        dst[(k + 2) * 64 + b] = v.z;
        dst[(k + 3) * 64 + b] = v.w;
    }
}

// ---------------------------------------------------------------------------
// Persistent BiLSTM recurrence, dataflow-synchronized (poll-on-data).
// Grid 256 = 2 dirs x 128 ublocks; 512 threads (8 waves); all blocks
// co-resident (32 KB LDS, 40-80 VGPR) -> deadlock-free.
// hsT is pre-memset to 0xFF (float NaN pattern, unreachable for h=o*tanh(c)).
// Producers store h with relaxed agent-scope stores (no drain/flag/barrier);
// consumers poll their own 32 h-values until none is the sentinel. One
// __syncthreads per step (double-buffered partial exchange).
// ---------------------------------------------------------------------------
__global__ __launch_bounds__(512, 2) void lstm_persist(
    const float* __restrict__ embT,
    const float* __restrict__ Wih_f, const float* __restrict__ Whh_f,
    const float* __restrict__ bih_f, const float* __restrict__ bhh_f,
    const float* __restrict__ Wih_b, const float* __restrict__ Whh_b,
    const float* __restrict__ bih_b, const float* __restrict__ bhh_b,
    const float* __restrict__ h0, const float* __restrict__ c0,
    float* __restrict__ hsTf, float* __restrict__ hsTb)
{
    __shared__ float buf[8192];    // 32 KB: double-buffered partial exchange
    const int tid  = threadIdx.x;
    const int b    = tid & 63;
    const int w    = tid >> 6;     // 0..7 K-chunk index
    const int bx   = blockIdx.x;
    const int dir  = bx & 1;
    const int ublk = bx >> 1;      // 0..127
    const int u0   = ublk * 2;

    const float* Wih = dir ? Wih_b : Wih_f;
    const float* Whh = dir ? Whh_b : Whh_f;
    const float* bih = dir ? bih_b : bih_f;
    const float* bhh = dir ? bhh_b : bhh_f;
    float* hsT = dir ? hsTb : hsTf;

    const int kbase = w * 32;
    const int kb_s  = __builtin_amdgcn_readfirstlane(kbase);

    // 8 gate-row weight bases (wave-uniform -> scalar loads via K$)
    const float* Wx0 = Wih + (size_t)(0 * 256 + u0    ) * EE + kb_s;
    const float* Wx1 = Wih + (size_t)(0 * 256 + u0 + 1) * EE + kb_s;
    const float* Wx2 = Wih + (size_t)(1 * 256 + u0    ) * EE + kb_s;
    const float* Wx3 = Wih + (size_t)(1 * 256 + u0 + 1) * EE + kb_s;
    const float* Wx4 = Wih + (size_t)(2 * 256 + u0    ) * EE + kb_s;
    const float* Wx5 = Wih + (size_t)(2 * 256 + u0 + 1) * EE + kb_s;
    const float* Wx6 = Wih + (size_t)(3 * 256 + u0    ) * EE + kb_s;
    const float* Wx7 = Wih + (size_t)(3 * 256 + u0 + 1) * EE + kb_s;
    const float* Wh0 = Whh + (size_t)(0 * 256 + u0    ) * HH + kb_s;
    const float* Wh1 = Whh + (size_t)(0 * 256 + u0 + 1) * HH + kb_s;
    const float* Wh2 = Whh + (size_t)(1 * 256 + u0    ) * HH + kb_s;
    const float* Wh3 = Whh + (size_t)(1 * 256 + u0 + 1) * HH + kb_s;
    const float* Wh4 = Whh + (size_t)(2 * 256 + u0    ) * HH + kb_s;
    const float* Wh5 = Whh + (size_t)(2 * 256 + u0 + 1) * HH + kb_s;
    const float* Wh6 = Whh + (size_t)(3 * 256 + u0    ) * HH + kb_s;
    const float* Wh7 = Whh + (size_t)(3 * 256 + u0 + 1) * HH + kb_s;

    // persistent cell state + biases (tid<128: uo = tid>>6, unit u0+uo)
    float c_reg = 0.0f;
    float bias0 = 0.f, bias1 = 0.f, bias2 = 0.f, bias3 = 0.f;
    if (tid < 128) {
        const int uo = tid >> 6;
        const int u  = u0 + uo;
        c_reg = c0[dir * BH + b * HH + u];
        bias0 = bih[0 * 256 + u] + bhh[0 * 256 + u];
        bias1 = bih[1 * 256 + u] + bhh[1 * 256 + u];
        bias2 = bih[2 * 256 + u] + bhh[2 * 256 + u];
        bias3 = bih[3 * 256 + u] + bhh[3 * 256 + u];
    }

    for (int step = 0; step < TT; ++step) {
        const int t_emb = dir ? (TT - 1 - step) : step;

        float acc0 = 0.f, acc1 = 0.f, acc2 = 0.f, acc3 = 0.f;
        float acc4 = 0.f, acc5 = 0.f, acc6 = 0.f, acc7 = 0.f;

        // ---- x dots: plain cached loads from embT (no h dependency;
        //      overlaps the producer lag of the h values below) ----
        {
            const float* xs = embT + (size_t)t_emb * KB16 + kbase * 64 + b;
            #pragma unroll 8
            for (int k = 0; k < 32; ++k) {
                const float x = xs[k * 64];
                acc0 = fmaf(x, Wx0[k], acc0);
                acc1 = fmaf(x, Wx1[k], acc1);
                acc2 = fmaf(x, Wx2[k], acc2);
                acc3 = fmaf(x, Wx3[k], acc3);
                acc4 = fmaf(x, Wx4[k], acc4);
                acc5 = fmaf(x, Wx5[k], acc5);
                acc6 = fmaf(x, Wx6[k], acc6);
                acc7 = fmaf(x, Wx7[k], acc7);
            }
        }

        // ---- h values: poll-on-data (sentinel 0xFFFFFFFF) ----
        unsigned hv[32];
        if (step == 0) {
            const float* hp = h0 + dir * BH + b * HH + kbase;  // contiguous
            #pragma unroll
            for (int k = 0; k < 32; ++k) hv[k] = __float_as_uint(hp[k]);
        } else {
            const int t_prev = dir ? (t_emb + 1) : (t_emb - 1);
            const unsigned* hsrc =
                (const unsigned*)(hsT + (size_t)t_prev * KB16 + kbase * 64 + b);
            for (;;) {
                #pragma unroll
                for (int k = 0; k < 32; ++k)
                    hv[k] = __hip_atomic_load(hsrc + k * 64, __ATOMIC_RELAXED,
                                              __HIP_MEMORY_SCOPE_AGENT);
                unsigned bad = 0;
                #pragma unroll
                for (int k = 0; k < 32; ++k) bad |= (hv[k] == 0xFFFFFFFFu);
                if (!__any(bad)) break;
                __builtin_amdgcn_s_sleep(1);
            }
        }

        // ---- h dots ----
        #pragma unroll 8
        for (int k = 0; k < 32; ++k) {
            const float h = __uint_as_float(hv[k]);
            acc0 = fmaf(h, Wh0[k], acc0);
            acc1 = fmaf(h, Wh1[k], acc1);
            acc2 = fmaf(h, Wh2[k], acc2);
            acc3 = fmaf(h, Wh3[k], acc3);
            acc4 = fmaf(h, Wh4[k], acc4);
            acc5 = fmaf(h, Wh5[k], acc5);
            acc6 = fmaf(h, Wh6[k], acc6);
            acc7 = fmaf(h, Wh7[k], acc7);
        }

        // ---- exchange partials: pb[w][dot], dot = r*64 + b (double-buffered) ----
        float* pb = buf + ((step & 1) << 12);
        pb[w * 512 + 0 * 64 + b] = acc0;
        pb[w * 512 + 1 * 64 + b] = acc1;
        pb[w * 512 + 2 * 64 + b] = acc2;
        pb[w * 512 + 3 * 64 + b] = acc3;
        pb[w * 512 + 4 * 64 + b] = acc4;
        pb[w * 512 + 5 * 64 + b] = acc5;
        pb[w * 512 + 6 * 64 + b] = acc6;
        pb[w * 512 + 7 * 64 + b] = acc7;
        __syncthreads();   // the ONLY per-step block sync

        // ---- cell update (128 threads: b, uo); fire-and-forget h store ----
        if (tid < 128) {
            const int uo = tid >> 6;
            const int u  = u0 + uo;
            float p0 = bias0, p1 = bias1, p2 = bias2, p3 = bias3;
            #pragma unroll
            for (int ww = 0; ww < 8; ++ww) {
                p0 += pb[ww * 512 + (0 * 2 + uo) * 64 + b];
                p1 += pb[ww * 512 + (1 * 2 + uo) * 64 + b];
                p2 += pb[ww * 512 + (2 * 2 + uo) * 64 + b];
                p3 += pb[ww * 512 + (3 * 2 + uo) * 64 + b];
            }
            const float ig = 1.0f / (1.0f + expf(-p0));
            const float fg = 1.0f / (1.0f + expf(-p1));
            const float gg = tanhf(p2);
            const float og = 1.0f / (1.0f + expf(-p3));
            c_reg = fg * c_reg + ig * gg;
            const float h = og * tanhf(c_reg);
            unsigned* dst = (unsigned*)(hsT + (size_t)t_emb * KB16 + u * 64 + b);
            __hip_atomic_store(dst, __float_as_uint(h), __ATOMIC_RELAXED,
                               __HIP_MEMORY_SCOPE_AGENT);
        }
    }
}

// ---------------------------------------------------------------------------
// scores[t,b,s] = sum_k hsTf[t][k][b]*W_lin[s][k] + hsTb[t][k][b]*W_lin[s][256+k]
//                 + b_lin[s].  One block per t.
// ---------------------------------------------------------------------------
__global__ __launch_bounds__(256) void scores_kernel(
    const float* __restrict__ hsTf, const float* __restrict__ hsTb,
    const float* __restrict__ W_lin, const float* __restrict__ b_lin,
    float* __restrict__ scores)
{
    __shared__ float As[128 * 64];   // As[k][b]
    __shared__ float Ws[128 * 64];   // Ws[k][s]
    const int t   = blockIdx.x;
    const int tid = threadIdx.x;
    const int bl  = tid & 63;
    const int kc  = tid >> 6;        // 0..3
    const int tb  = tid & 15;
    const int ts  = tid >> 4;

    float acc[4][4] = {};

    for (int chunk = 0; chunk < 4; ++chunk) {
        const int koff = chunk * 128;
        const float* srcA = (koff < 256)
            ? (hsTf + (size_t)t * KB16 + (size_t)koff * 64)
            : (hsTb + (size_t)t * KB16 + (size_t)(koff - 256) * 64);
        const float4* sA4 = (const float4*)srcA;
        float4* As4 = (float4*)As;
        #pragma unroll
        for (int i = 0; i < 8; ++i) As4[tid + i * 256] = sA4[tid + i * 256];
        const float4* wl4 = (const float4*)(W_lin + koff);  // row pitch 128 f4
        #pragma unroll
        for (int it = 0; it < 8; ++it) {
            const int k4 = it * 4 + kc;
            float4 wv = wl4[bl * 128 + k4];
            const int k = k4 * 4;
            Ws[(k + 0) * 64 + bl] = wv.x; Ws[(k + 1) * 64 + bl] = wv.y;
            Ws[(k + 2) * 64 + bl] = wv.z; Ws[(k + 3) * 64 + bl] = wv.w;
        }
        __syncthreads();
        #pragma unroll 4
        for (int k = 0; k < 128; ++k) {
            const float4 av = *(const float4*)&As[k * 64 + tb * 4];
            const float4 bv = *(const float4*)&Ws[k * 64 + ts * 4];
            acc[0][0] += av.x * bv.x; acc[0][1] += av.x * bv.y; acc[0][2] += av.x * bv.z; acc[0][3] += av.x * bv.w;
            acc[1][0] += av.y * bv.x; acc[1][1] += av.y * bv.y; acc[1][2] += av.y * bv.z; acc[1][3] += av.y * bv.w;
            acc[2][0] += av.z * bv.x; acc[2][1] += av.z * bv.y; acc[2][2] += av.z * bv.z; acc[2][3] += av.z * bv.w;
            acc[3][0] += av.w * bv.x; acc[3][1] += av.w * bv.y; acc[3][2] += av.w * bv.z; acc[3][3] += av.w * bv.w;
        }
        __syncthreads();
    }

    #pragma unroll
    for (int i = 0; i < 4; ++i) {
        const int bb = tb * 4 + i;
        #pragma unroll
        for (int j = 0; j < 4; ++j) {
            const int ss = ts * 4 + j;
            scores[(size_t)t * (BB * SS) + bb * SS + ss] = acc[i][j] + b_lin[ss];
        }
    }
}

// ---------------------------------------------------------------------------
// Viterbi forward + backtrace. One block per batch b; 256 threads:
// thread (s = tid&63, q = tid>>6) scans prev-states p in [q*16,(q+1)*16).
// pairwise rows held in registers. Ascending strict-'>' scan + ascending
// strict-'>' quarter combine == numpy first-index argmax.
// ---------------------------------------------------------------------------
__global__ __launch_bounds__(256) void viterbi_kernel(
    const float* __restrict__ scores, const float* __restrict__ pairwise,
    const float* __restrict__ start, const float* __restrict__ stop,
    float* __restrict__ out)
{
    __shared__ float delta[2][64];
    __shared__ float part[4][64];
    __shared__ int   pidx[4][64];
    __shared__ unsigned char bps[511 * 64];
    __shared__ float fin[64];

    const int b   = blockIdx.x;
    const int tid = threadIdx.x;
    const int s   = tid & 63;
    const int q   = tid >> 6;

    float pw[16];
    #pragma unroll
    for (int i = 0; i < 16; ++i)
        pw[i] = pairwise[(q * 16 + i) * 64 + s];

    if (q == 0) delta[0][s] = start[s] + scores[b * SS + s];
    __syncthreads();

    int cur = 0;
    for (int t = 1; t < TT; ++t) {
        float sc = 0.0f;
        if (q == 0) sc = scores[(size_t)t * (BB * SS) + b * SS + s];
        float best = -1e30f;
        int bp = q * 16;
        #pragma unroll
        for (int i = 0; i < 16; ++i) {
            const float v = delta[cur][q * 16 + i] + pw[i];   // broadcast read
            if (v > best) { best = v; bp = q * 16 + i; }
        }
        part[q][s] = best;
        pidx[q][s] = bp;
        __syncthreads();
        if (q == 0) {
            float m = part[0][s];
            int arg = pidx[0][s];
            #pragma unroll
            for (int qq = 1; qq < 4; ++qq) {
                const float v = part[qq][s];
                if (v > m) { m = v; arg = pidx[qq][s]; }
            }
            delta[cur ^ 1][s] = m + sc;
            bps[(t - 1) * 64 + s] = (unsigned char)arg;
        }
        cur ^= 1;
        __syncthreads();
    }

    if (q == 0) fin[s] = delta[cur][s] + stop[s];
    __syncthreads();

    if (tid == 0) {
        float m = fin[0];
        int arg = 0;
        for (int p = 1; p < 64; ++p)
            if (fin[p] > m) { m = fin[p]; arg = p; }
        out[b] = m;
        int st = arg;
        out[64 + 511 * 64 + b] = (float)st;
        for (int k = 510; k >= 0; --k) {
            st = bps[k * 64 + st];
            out[64 + k * 64 + b] = (float)st;
        }
    }
}

// ---------------------------------------------------------------------------
extern "C" void kernel_launch(void* const* d_in, const int* in_sizes, int n_in,
                              void* d_out, int out_size, void* d_ws, size_t ws_size,
                              hipStream_t stream)
{
    const int*   obs      = (const int*)d_in[0];
    const float* h0       = (const float*)d_in[1];
    const float* c0       = (const float*)d_in[2];
    const float* embed    = (const float*)d_in[3];
    const float* Wih_f    = (const float*)d_in[4];
    const float* Whh_f    = (const float*)d_in[5];
    const float* bih_f    = (const float*)d_in[6];
    const float* bhh_f    = (const float*)d_in[7];
    const float* Wih_b    = (const float*)d_in[8];
    const float* Whh_b    = (const float*)d_in[9];
    const float* bih_b    = (const float*)d_in[10];
    const float* bhh_b    = (const float*)d_in[11];
    const float* W_lin    = (const float*)d_in[12];
    const float* b_lin    = (const float*)d_in[13];
    const float* pairwise = (const float*)d_in[14];
    const float* start    = (const float*)d_in[15];
    const float* stop     = (const float*)d_in[16];
    (void)in_sizes; (void)n_in; (void)out_size; (void)ws_size;

    // ws layout (floats): embT | hsTf | hsTb | scores   (~104 MB)
    float* ws     = (float*)d_ws;
    float* embT   = ws;
    float* hsTf   = embT + (size_t)TT * KB16;
    float* hsTb   = hsTf + (size_t)TT * KB16;
    float* scores = hsTb + (size_t)TT * KB16;

    // sentinel-init hsTf+hsTb (contiguous, 64 MB): 0xFF bytes = float NaN
    hipMemsetAsync(hsTf, 0xFF, (size_t)2 * TT * KB16 * sizeof(float), stream);
    embT_prep<<<512, 256, 0, stream>>>(obs, embed, embT);
    lstm_persist<<<256, 512, 0, stream>>>(
        embT, Wih_f, Whh_f, bih_f, bhh_f, Wih_b, Whh_b, bih_b, bhh_b,
        h0, c0, hsTf, hsTb);
    scores_kernel<<<512, 256, 0, stream>>>(hsTf, hsTb, W_lin, b_lin, scores);
    viterbi_kernel<<<64, 256, 0, stream>>>(scores, pairwise, start, stop, (float*)d_out);
}